// Round 6
// baseline (423.248 us; speedup 1.0000x reference)
//
#include <hip/hip_runtime.h>
#include <stdint.h>

#define M_CH       384
#define TR         15
#define MARGIN     20
#define CHUNK_ROWS 16
#define BM_WORDS   192        // words per chunk = 16*384/32
#define WPR        12         // words per row = 384/32
#define WIN_ROWS   46         // CHUNK_ROWS + 2*TR

typedef float vfloat4 __attribute__((ext_vector_type(4)));  // native clang vec

// spread 8 bits of x to positions 0,4,8,...,28
__device__ __forceinline__ uint32_t spread4(uint32_t x) {
    x = (x | (x << 12)) & 0x000F000Fu;
    x = (x | (x << 6))  & 0x03030303u;
    x = (x | (x << 3))  & 0x11111111u;
    return x;
}

// ---------------- K1: streaming threshold pass (grid-stride, NT loads) ----
// Roles by blockIdx: [0, workBlocks) threshold; == workBlocks neighbor masks;
// > workBlocks: pre-fill output with -1 (emit overwrites [0,total)).
// Each wave-iteration covers a 2048-sample tile (512 float4 = 64 words):
// 8 coalesced 1-KB nontemporal loads in flight (stream is read exactly once
// -> do not allocate in L2/MALL), 32 ballots, then ALL 64 lanes build one
// word each and store 256 B contiguous (cacheable: validate re-reads it).
// Hot loop is guard-free: 14.4M float4 = 28125 tiles x 512 exactly.
__global__ __launch_bounds__(256)
void cand_kernel(const float* __restrict__ traces,
                 const float* __restrict__ locs,
                 long n4, long nwords, int workBlocks,
                 uint32_t* __restrict__ candWords,
                 uint32_t* __restrict__ nEntries,
                 uint8_t* __restrict__ entryWord,
                 uint32_t* __restrict__ entryMask,
                 int maxdet, int* __restrict__ times, int* __restrict__ chans) {
    if ((int)blockIdx.x > workBlocks) {
        // ---- fill role: poison-proof init ----
        int i = ((int)blockIdx.x - workBlocks - 1) * 256 + threadIdx.x;
        if (i < maxdet) { times[i] = -1; chans[i] = -1; }
        return;
    }
    if ((int)blockIdx.x == workBlocks) {
        // ---- neighbor-mask role (one block) ----
        __shared__ float lx[M_CH], ly[M_CH];
        const int t = threadIdx.x;
        for (int c = t; c < M_CH; c += 256) {
            lx[c] = locs[2 * c];
            ly[c] = locs[2 * c + 1];
        }
        __syncthreads();
        for (int c0 = t; c0 < M_CH; c0 += 256) {
            float x = lx[c0], y = ly[c0];
            int ne = 0;
            for (int k = 0; k < WPR; ++k) {
                uint32_t mk = 0;
                #pragma unroll
                for (int b = 0; b < 32; ++b) {
                    int c = k * 32 + b;
                    float dx = x - lx[c], dy = y - ly[c];
                    if (sqrtf(dx * dx + dy * dy) <= 100.0f) mk |= 1u << b;
                }
                if (mk) {
                    entryWord[c0 * WPR + ne] = (uint8_t)k;
                    entryMask[c0 * WPR + ne] = mk;
                    ne++;
                }
            }
            nEntries[c0] = (uint32_t)ne;
        }
        return;
    }

    const int lane = threadIdx.x & 63;
    const long nTiles = (nwords + 63) >> 6;     // 28125
    const long nTilesFull = n4 >> 9;            // full 512-float4 tiles (=28125)
    const long wv0 = (((long)blockIdx.x * 256) + threadIdx.x) >> 6;
    const long nwv = (long)workBlocks * 4;

    for (long tile = wv0; tile < nTiles; tile += nwv) {
        const long f0 = tile << 9;              // first float4 of tile
        const vfloat4* p = (const vfloat4*)traces + f0 + lane;
        vfloat4 v0, v1, v2, v3, v4, v5, v6, v7;
        if (tile < nTilesFull) {
            // guard-free fast path, nontemporal (no cache allocation)
            v0 = __builtin_nontemporal_load(p + 0 * 64);
            v1 = __builtin_nontemporal_load(p + 1 * 64);
            v2 = __builtin_nontemporal_load(p + 2 * 64);
            v3 = __builtin_nontemporal_load(p + 3 * 64);
            v4 = __builtin_nontemporal_load(p + 4 * 64);
            v5 = __builtin_nontemporal_load(p + 5 * 64);
            v6 = __builtin_nontemporal_load(p + 6 * 64);
            v7 = __builtin_nontemporal_load(p + 7 * 64);
        } else {
            vfloat4 z = (vfloat4)0.0f;
            v0 = v1 = v2 = v3 = v4 = v5 = v6 = v7 = z;
            long i0 = f0 + lane;
            if (i0 + 0 * 64 < n4) v0 = p[0 * 64];
            if (i0 + 1 * 64 < n4) v1 = p[1 * 64];
            if (i0 + 2 * 64 < n4) v2 = p[2 * 64];
            if (i0 + 3 * 64 < n4) v3 = p[3 * 64];
            if (i0 + 4 * 64 < n4) v4 = p[4 * 64];
            if (i0 + 5 * 64 < n4) v5 = p[5 * 64];
            if (i0 + 6 * 64 < n4) v6 = p[6 * 64];
            if (i0 + 7 * 64 < n4) v7 = p[7 * 64];
        }
        uint64_t B00 = __ballot(v0[0] <= -3.0f), B01 = __ballot(v0[1] <= -3.0f),
                 B02 = __ballot(v0[2] <= -3.0f), B03 = __ballot(v0[3] <= -3.0f);
        uint64_t B10 = __ballot(v1[0] <= -3.0f), B11 = __ballot(v1[1] <= -3.0f),
                 B12 = __ballot(v1[2] <= -3.0f), B13 = __ballot(v1[3] <= -3.0f);
        uint64_t B20 = __ballot(v2[0] <= -3.0f), B21 = __ballot(v2[1] <= -3.0f),
                 B22 = __ballot(v2[2] <= -3.0f), B23 = __ballot(v2[3] <= -3.0f);
        uint64_t B30 = __ballot(v3[0] <= -3.0f), B31 = __ballot(v3[1] <= -3.0f),
                 B32 = __ballot(v3[2] <= -3.0f), B33 = __ballot(v3[3] <= -3.0f);
        uint64_t B40 = __ballot(v4[0] <= -3.0f), B41 = __ballot(v4[1] <= -3.0f),
                 B42 = __ballot(v4[2] <= -3.0f), B43 = __ballot(v4[3] <= -3.0f);
        uint64_t B50 = __ballot(v5[0] <= -3.0f), B51 = __ballot(v5[1] <= -3.0f),
                 B52 = __ballot(v5[2] <= -3.0f), B53 = __ballot(v5[3] <= -3.0f);
        uint64_t B60 = __ballot(v6[0] <= -3.0f), B61 = __ballot(v6[1] <= -3.0f),
                 B62 = __ballot(v6[2] <= -3.0f), B63 = __ballot(v6[3] <= -3.0f);
        uint64_t B70 = __ballot(v7[0] <= -3.0f), B71 = __ballot(v7[1] <= -3.0f),
                 B72 = __ballot(v7[2] <= -3.0f), B73 = __ballot(v7[3] <= -3.0f);

        const int k  = lane >> 3;          // ballot group 0..7
        const int sh = (lane & 7) * 8;     // byte within the ballot
        uint64_t b0 = (k & 4) ? ((k & 2) ? ((k & 1) ? B70 : B60) : ((k & 1) ? B50 : B40))
                              : ((k & 2) ? ((k & 1) ? B30 : B20) : ((k & 1) ? B10 : B00));
        uint64_t b1 = (k & 4) ? ((k & 2) ? ((k & 1) ? B71 : B61) : ((k & 1) ? B51 : B41))
                              : ((k & 2) ? ((k & 1) ? B31 : B21) : ((k & 1) ? B11 : B01));
        uint64_t b2 = (k & 4) ? ((k & 2) ? ((k & 1) ? B72 : B62) : ((k & 1) ? B52 : B42))
                              : ((k & 2) ? ((k & 1) ? B32 : B22) : ((k & 1) ? B12 : B02));
        uint64_t b3 = (k & 4) ? ((k & 2) ? ((k & 1) ? B73 : B63) : ((k & 1) ? B53 : B43))
                              : ((k & 2) ? ((k & 1) ? B33 : B23) : ((k & 1) ? B13 : B03));
        uint32_t w = spread4((uint32_t)(b0 >> sh) & 0xFFu)
                   | (spread4((uint32_t)(b1 >> sh) & 0xFFu) << 1)
                   | (spread4((uint32_t)(b2 >> sh) & 0xFFu) << 2)
                   | (spread4((uint32_t)(b3 >> sh) & 0xFFu) << 3);
        long wIdx = (tile << 6) + lane;
        if (wIdx < nwords) candWords[wIdx] = w;
    }
}

// ---------------- K2: validate via LDS-staged window + per-chunk count ----
// Block = 192 threads = one 16-row chunk; window (46 rows x 12 words) is
// contiguous in candWords -> coalesced stage into LDS. Fast path: per
// candidate/entry a 31-word OR from LDS; zero global loads when clean.
// Slow path (rare): value comparison on actual hits only.
__global__ __launch_bounds__(192)
void validate_count_kernel(const float* __restrict__ traces, int N, long nwords,
                           const uint32_t* __restrict__ nEntries,
                           const uint8_t* __restrict__ entryWord,
                           const uint32_t* __restrict__ entryMask,
                           const uint32_t* __restrict__ candWords,
                           uint32_t* __restrict__ validOut,
                           uint32_t* __restrict__ chunkCounts) {
    __shared__ uint32_t win[WIN_ROWS * WPR];   // 552 words = 2.2 KB
    __shared__ uint32_t red[3];
    const int t = threadIdx.x;
    const int r0 = (int)blockIdx.x * CHUNK_ROWS;

    {
        const long gbase = (long)(r0 - TR) * WPR;
        #pragma unroll
        for (int i0 = 0; i0 < WIN_ROWS * WPR; i0 += 192) {
            int i = i0 + t;
            if (i < WIN_ROWS * WPR) {
                long g = gbase + i;
                win[i] = (g >= 0 && g < nwords) ? candWords[g] : 0u;
            }
        }
    }
    __syncthreads();

    const int lr = t / WPR;        // local row 0..15
    const int wi = t - lr * WPR;   // word-in-row 0..11
    const int r  = r0 + lr;
    const long w = (long)blockIdx.x * BM_WORDS + t;

    uint32_t out = 0;
    if (w < nwords) {
        uint32_t word = win[(lr + TR) * WPR + wi];
        if (word && r >= MARGIN && r < N - MARGIN) {
            out = word;
            uint32_t tmp = word;
            while (tmp) {
                int bit = __ffs(tmp) - 1;
                tmp &= tmp - 1;
                const int c = wi * 32 + bit;
                const uint32_t selfbit = 1u << bit;
                const int ne = (int)nEntries[c];

                // ---- fast pass: any competitor bit anywhere in window? ----
                uint32_t anyComp = 0;
                for (int k = 0; k < ne; ++k) {
                    int wiE = (int)entryWord[c * WPR + k];
                    uint32_t em = entryMask[c * WPR + k];
                    const uint32_t* colp = &win[lr * WPR + wiE];
                    uint32_t orw = 0;
                    #pragma unroll
                    for (int dt = 0; dt < 31; ++dt) {
                        uint32_t h = colp[dt * WPR];
                        if (dt == TR) h &= (wiE == wi) ? ~selfbit : 0xFFFFFFFFu;
                        orw |= h & em;
                    }
                    anyComp |= orw;
                }

                if (anyComp) {
                    // ---- slow path: value comparison on actual hits ----
                    float raw = traces[(long)r * M_CH + c];
                    bool bad = false;
                    for (int k = 0; k < ne && !bad; ++k) {
                        int wiE = (int)entryWord[c * WPR + k];
                        uint32_t em = entryMask[c * WPR + k];
                        const uint32_t* colp = &win[lr * WPR + wiE];
                        #pragma unroll
                        for (int dt = 0; dt < 31; ++dt) {
                            uint32_t h = colp[dt * WPR] & em;
                            if (dt == TR && wiE == wi) h &= ~selfbit;
                            while (h) {
                                int b2 = __ffs(h) - 1;
                                h &= h - 1;
                                float v = traces[(long)(r - TR + dt) * M_CH + wiE * 32 + b2];
                                if (v < raw) bad = true;
                            }
                        }
                    }
                    if (bad) out &= ~selfbit;
                }
            }
        }
        validOut[w] = out;
    }
    int pc = __popc(out);
    #pragma unroll
    for (int off = 32; off; off >>= 1) pc += __shfl_xor(pc, off, 64);
    if ((t & 63) == 0) red[t >> 6] = (uint32_t)pc;
    __syncthreads();
    if (t == 0) chunkCounts[blockIdx.x] = red[0] + red[1] + red[2];
}

// ---------------- K3: emit with REDUNDANT prefix (no scan kernel) --------
// Block handles 4 consecutive chunks (one per wave). Its base prefix is
// computed locally: 256 threads cooperatively sum counts[0..c0) — 37.5 KB
// of L1/L2-resident data, zero atomics, zero inter-block dependencies.
__global__ __launch_bounds__(256)
void emit_kernel(const uint32_t* __restrict__ validOut,
                 const uint32_t* __restrict__ chunkCounts,
                 int nchunk, int maxdet,
                 int* __restrict__ times, int* __restrict__ chans) {
    __shared__ uint32_t sred[4];
    __shared__ uint32_t cnts4[4];
    const int t = threadIdx.x;
    const int lane = t & 63;
    const int wv   = t >> 6;
    const int c0 = (int)blockIdx.x * 4;

    if (t < 4) cnts4[t] = (c0 + t < nchunk) ? chunkCounts[c0 + t] : 0u;

    // cooperative exclusive prefix: sum counts[0..c0)
    uint32_t part = 0;
    for (int i = t; i < c0; i += 256) part += chunkCounts[i];
    #pragma unroll
    for (int off = 32; off; off >>= 1) part += __shfl_xor(part, off, 64);
    if (lane == 0) sred[wv] = part;
    __syncthreads();
    uint32_t base0 = sred[0] + sred[1] + sred[2] + sred[3];

    const int chunkId = c0 + wv;
    if (chunkId >= nchunk) return;
    uint32_t basePref = base0;
    #pragma unroll
    for (int k = 0; k < 3; ++k) if (k < wv) basePref += cnts4[k];

    const uint32_t* wp = validOut + (long)chunkId * BM_WORDS + lane * 3;
    uint32_t b0 = wp[0], b1 = wp[1], b2 = wp[2];
    int local = __popc(b0) + __popc(b1) + __popc(b2);

    int s = local;
    #pragma unroll
    for (int off = 1; off < 64; off <<= 1) {
        int v = __shfl_up(s, off, 64);
        if (lane >= off) s += v;
    }
    int base = (int)basePref + (s - local);
    int r0 = chunkId * CHUNK_ROWS;

    uint32_t words[3] = { b0, b1, b2 };
    #pragma unroll
    for (int q = 0; q < 3; ++q) {
        uint32_t x = words[q];
        int fbase = (lane * 3 + q) * 32;
        while (x) {
            int b = __ffs(x) - 1;
            x &= x - 1;
            int f = fbase + b;
            int n = f / M_CH;
            int ch = f - n * M_CH;
            if (base < maxdet) {
                times[base] = r0 + n;
                chans[base] = ch;
            }
            base++;
        }
    }
}

extern "C" void kernel_launch(void* const* d_in, const int* in_sizes, int n_in,
                              void* d_out, int out_size, void* d_ws, size_t ws_size,
                              hipStream_t stream) {
    const float* traces = (const float*)d_in[0];
    const float* locs   = (const float*)d_in[1];
    const int M = M_CH;
    const int N = in_sizes[0] / M;            // 150000
    const long nsamp = (long)N * M;           // 57,600,000
    const int maxdet = out_size / 2;          // 100000
    int* times = (int*)d_out;
    int* chans = times + maxdet;

    const long n4     = nsamp / 4;                          // 14,400,000
    const long nwords = nsamp / 32;                         // 1,800,000
    const int  nchunk = (N + CHUNK_ROWS - 1) / CHUNK_ROWS;  // 9375

    char* ws = (char*)d_ws;
    uint32_t* nEntries    = (uint32_t*)(ws + 0);            // 1536
    uint8_t*  entryWord   = (uint8_t*)(ws + 1536);          // 4608   -> 6144
    uint32_t* entryMask   = (uint32_t*)(ws + 6144);         // 18432  -> 24576
    uint32_t* chunkCounts = (uint32_t*)(ws + 24576);        // 37500  -> 65536 (pad)
    uint32_t* candWords   = (uint32_t*)(ws + 65536);        // 7.2 MB -> 7265536
    uint32_t* validOut    = (uint32_t*)(ws + 7265536);      // 7.2 MB -> 14.5 MB

    // persistent grid-stride threshold pass: 2048 work blocks = 8 blocks/CU,
    // each wave iterates ~3.4 tiles of 2048 samples; +1 nbr block; +fill.
    const int  workBlocks = 2048;
    const int  fillBlocks = (maxdet + 255) / 256;           // 391
    cand_kernel<<<workBlocks + 1 + fillBlocks, 256, 0, stream>>>(
        traces, locs, n4, nwords, workBlocks,
        candWords, nEntries, entryWord, entryMask,
        maxdet, times, chans);

    validate_count_kernel<<<nchunk, BM_WORDS, 0, stream>>>(
        traces, N, nwords, nEntries, entryWord, entryMask, candWords,
        validOut, chunkCounts);

    const int emitBlocks = (nchunk + 3) / 4;                // 2344
    emit_kernel<<<emitBlocks, 256, 0, stream>>>(
        validOut, chunkCounts, nchunk, maxdet, times, chans);
}